// Round 10
// baseline (153.127 us; speedup 1.0000x reference)
//
#include <hip/hip_runtime.h>

#define BC 16
#define NN 2048
#define FF 128
#define DD 128
#define NEDGES 65536
#define NEG_INF -1e16f
#define LEAK 0.1f
#define CAPR 128   // per-row in-degree cap; P(Poisson(32) > 128) ~ 1e-35

typedef float v4f __attribute__((ext_vector_type(4)));

// ---------------- Kernel 1 (fused): edge atomicOr + z = h @ W ------------
// blocks 0..255: set adjacency bits (mask pre-zeroed by hipMemsetAsync).
// blocks 256..1279: register-tiled zgemm, one [32 x 128] tile of z each.
__global__ void __launch_bounds__(256) zedge_kernel(const float* __restrict__ h,
                                                    const float* __restrict__ W,
                                                    float* __restrict__ z,
                                                    const int* __restrict__ row,
                                                    const int* __restrict__ col,
                                                    unsigned int* __restrict__ mask) {
    const int tid = threadIdx.x;
    const int blk = blockIdx.x;

    if (blk < 256) {   // ---- edge part
        const int e = blk * 256 + tid;
        const unsigned int key = (unsigned int)row[e] * NN + (unsigned int)col[e];
        atomicOr(&mask[key >> 5], 1u << (key & 31u));
        return;
    }

    // ---- zgemm part
    __shared__ float hs[32][FF];   // 16 KB
    const size_t row0 = (size_t)(blk - 256) * 32;
    const float4* hv = (const float4*)(h + row0 * FF);
    float4* hsv = (float4*)&hs[0][0];
#pragma unroll
    for (int i = 0; i < 4; ++i) hsv[tid + 256 * i] = hv[tid + 256 * i];
    __syncthreads();

    const int c0 = (tid & 31) * 4;
    const int r0 = (tid >> 5) * 4;
    float acc[4][4] = {};
    for (int f = 0; f < FF; f += 4) {
        float4 a[4], bb[4];
#pragma unroll
        for (int r = 0; r < 4; ++r) a[r] = *(const float4*)&hs[r0 + r][f];
#pragma unroll
        for (int k = 0; k < 4; ++k) bb[k] = *(const float4*)&W[(f + k) * DD + c0];
#pragma unroll
        for (int r = 0; r < 4; ++r) {
            acc[r][0] += a[r].x * bb[0].x + a[r].y * bb[1].x + a[r].z * bb[2].x + a[r].w * bb[3].x;
            acc[r][1] += a[r].x * bb[0].y + a[r].y * bb[1].y + a[r].z * bb[2].y + a[r].w * bb[3].y;
            acc[r][2] += a[r].x * bb[0].z + a[r].y * bb[1].z + a[r].z * bb[2].z + a[r].w * bb[3].z;
            acc[r][3] += a[r].x * bb[0].w + a[r].y * bb[1].w + a[r].z * bb[2].w + a[r].w * bb[3].w;
        }
    }
#pragma unroll
    for (int r = 0; r < 4; ++r)
        *(float4*)&z[(row0 + r0 + r) * DD + c0] =
            make_float4(acc[r][0], acc[r][1], acc[r][2], acc[r][3]);
}

// ---------------- Kernel 2: bitmask -> sorted CSR, zero atomics ----------
__global__ void __launch_bounds__(256) csr_kernel(const unsigned int* __restrict__ mask,
                                                  unsigned short* __restrict__ hits_g,
                                                  int* __restrict__ deg) {
    const int tid = threadIdx.x, wv = tid >> 6, ln = tid & 63;
    const int n = blockIdx.x * 4 + wv;
    unsigned int bits = mask[n * 64 + ln];
    const int cnt = __popc(bits);
    int pre = cnt;
#pragma unroll
    for (int off = 1; off <= 32; off <<= 1) {
        const int t = __shfl_up(pre, off, 64);
        if (ln >= off) pre += t;
    }
    if (ln == 63) deg[n] = pre;
    int slot = pre - cnt;
    while (bits) {
        const int bit = __ffs(bits) - 1;
        bits &= bits - 1;
        if (slot < CAPR) hits_g[n * CAPR + slot] = (unsigned short)(ln * 32 + bit);
        ++slot;
    }
}

// ---------------- Kernel 3: single-pass online softmax, pipelined --------
// One wave per (b,n) row, 4 independent waves/block, no LDS/barriers.
// b-swizzle pins 2 batches of z per XCD L2. Lane = (eq 0..7, hq 0..7).
// R9->R10: (1) v4f ext-vector arithmetic so the backend can emit
// v_pk_fma_f32 (2 fp32 MACs/inst); (2) explicit next-chunk prefetch into
// named registers (w0..w3) so the L2 gather latency overlaps compute.
// All state is named scalars/vectors — nothing for promote-alloca to demote.
__global__ void __launch_bounds__(256) gat_kernel(const float* __restrict__ z,
                                                  const unsigned short* __restrict__ hits_g,
                                                  const int* __restrict__ deg,
                                                  float* __restrict__ out) {
    const int tid = threadIdx.x, wv = tid >> 6, ln = tid & 63;
    const int blk = blockIdx.x;
    const int b = ((blk & 7) << 1) | (wv & 1);
    const int n = ((blk >> 3) << 1) | (wv >> 1);
    const int eq = ln >> 3, hq = ln & 7;

    const float* zb = z + ((size_t)b << 18);   // b*2048*128
    const int nh = min(deg[n], CAPR);
    const unsigned short* hrow = hits_g + n * CAPR;

    const v4f* znp = (const v4f*)(zb + ((size_t)n << 7) + (hq << 4));
    const v4f a0 = znp[0], a1 = znp[1], a2 = znp[2], a3 = znp[3];

    float m = NEG_INF, l = 0.f;
    v4f acc0 = {0.f, 0.f, 0.f, 0.f}, acc1 = acc0, acc2 = acc0, acc3 = acc0;

    if (nh > 0) {
        // prologue: load chunk 0
        int he = hrow[min(eq, nh - 1)];
        const v4f* zc = (const v4f*)(zb + ((size_t)he << 7) + (hq << 4));
        v4f v0 = zc[0], v1 = zc[1], v2 = zc[2], v3 = zc[3];

        for (int c0 = 0; c0 < nh; c0 += 8) {
            // ---- prefetch chunk c0+8 (wave-uniform guard)
            v4f w0 = v0, w1 = v1, w2 = v2, w3 = v3;
            const int nx = c0 + 8;
            if (nx < nh) {
                const int hen = hrow[min(nx + eq, nh - 1)];
                const v4f* zn2 = (const v4f*)(zb + ((size_t)hen << 7) + (hq << 4));
                w0 = zn2[0]; w1 = zn2[1]; w2 = zn2[2]; w3 = zn2[3];
            }

            // ---- score: packed dot over this lane's 16 dims
            v4f d4 = a0 * v0;
            d4 += a1 * v1;
            d4 += a2 * v2;
            d4 += a3 * v3;
            float pt = (d4.x + d4.y) + (d4.z + d4.w);
            pt += __shfl_xor(pt, 1, 64);
            pt += __shfl_xor(pt, 2, 64);
            pt += __shfl_xor(pt, 4, 64);             // full 128-dim dot
            float sv = pt > 0.f ? pt : LEAK * pt;    // leaky_relu(0.1)
            const int e = c0 + eq;
            if (sv == 0.f || e >= nh) sv = NEG_INF;  // masked_fill / pad

            // ---- lane-local online softmax (short carried chain)
            const float mnew = fmaxf(m, sv);
            const float alpha = __expf(m - mnew);    // 1 while m==mnew==NEG_INF
            const float pr = __expf(sv - mnew);
            l = l * alpha + pr;
            acc0 = acc0 * alpha + v0 * pr;
            acc1 = acc1 * alpha + v1 * pr;
            acc2 = acc2 * alpha + v2 * pr;
            acc3 = acc3 * alpha + v3 * pr;
            m = mnew;

            v0 = w0; v1 = w1; v2 = w2; v3 = w3;
        }
    }

    // ---- cross-eq merge: global row max, rescale, sum ----
    float M = m;
#pragma unroll
    for (int off = 8; off <= 32; off <<= 1) M = fmaxf(M, __shfl_xor(M, off, 64));

    if (nh > 0 && M > 0.5f * NEG_INF) {
        const float al = __expf(m - M);              // 0 for all-pad lanes
        l *= al;
        acc0 *= al; acc1 *= al; acc2 *= al; acc3 *= al;
#pragma unroll
        for (int off = 8; off <= 32; off <<= 1) {
            l += __shfl_xor(l, off, 64);
            acc0.x += __shfl_xor(acc0.x, off, 64); acc0.y += __shfl_xor(acc0.y, off, 64);
            acc0.z += __shfl_xor(acc0.z, off, 64); acc0.w += __shfl_xor(acc0.w, off, 64);
            acc1.x += __shfl_xor(acc1.x, off, 64); acc1.y += __shfl_xor(acc1.y, off, 64);
            acc1.z += __shfl_xor(acc1.z, off, 64); acc1.w += __shfl_xor(acc1.w, off, 64);
            acc2.x += __shfl_xor(acc2.x, off, 64); acc2.y += __shfl_xor(acc2.y, off, 64);
            acc2.z += __shfl_xor(acc2.z, off, 64); acc2.w += __shfl_xor(acc2.w, off, 64);
            acc3.x += __shfl_xor(acc3.x, off, 64); acc3.y += __shfl_xor(acc3.y, off, 64);
            acc3.z += __shfl_xor(acc3.z, off, 64); acc3.w += __shfl_xor(acc3.w, off, 64);
        }
        const float inv = 1.f / l;
        acc0 *= inv; acc1 *= inv; acc2 *= inv; acc3 *= inv;
    } else {
        // no valid edge: softmax over uniform -1e16 row -> mean of z[b]
        acc0 = (v4f){0.f, 0.f, 0.f, 0.f}; acc1 = acc0; acc2 = acc0; acc3 = acc0;
        for (int mm = 0; mm < NN; ++mm) {
            const v4f* zr = (const v4f*)(zb + ((size_t)mm << 7) + (hq << 4));
            acc0 += zr[0]; acc1 += zr[1]; acc2 += zr[2]; acc3 += zr[3];
        }
        const float s = 1.f / NN;
        acc0 *= s; acc1 *= s; acc2 *= s; acc3 *= s;
    }

    // store: lanes with eq<4 write float4 #eq of their hq slice (512 B/row)
    if (eq < 4) {
        v4f o = acc0;
        if (eq == 1) o = acc1;
        if (eq == 2) o = acc2;
        if (eq == 3) o = acc3;
        *(v4f*)(out + (((size_t)b * NN + n) << 7) + (hq << 4) + (eq << 2)) = o;
    }
}

// ---------------- launcher ----------------
extern "C" void kernel_launch(void* const* d_in, const int* in_sizes, int n_in,
                              void* d_out, int out_size, void* d_ws, size_t ws_size,
                              hipStream_t stream) {
    const float* h = (const float*)d_in[0];
    const float* W = (const float*)d_in[1];
    const int* row = (const int*)d_in[2];
    const int* col = (const int*)d_in[3];
    float* out = (float*)d_out;

    char* ws = (char*)d_ws;
    float* z = (float*)ws;                                                     // 16 MB
    unsigned int* mask = (unsigned int*)(ws + (size_t)16 * 1024 * 1024);       // 512 KB
    unsigned short* hits_g = (unsigned short*)(ws + (size_t)16 * 1024 * 1024 + 512 * 1024); // 512 KB
    int* deg = (int*)(ws + (size_t)17 * 1024 * 1024);                          // 8 KB

    hipMemsetAsync(mask, 0, (size_t)NN * NN / 8, stream);   // DMA, ~2 us
    zedge_kernel<<<1280, 256, 0, stream>>>(h, W, z, row, col, mask);
    csr_kernel<<<NN / 4, 256, 0, stream>>>(mask, hits_g, deg);
    gat_kernel<<<(BC * NN) / 4, 256, 0, stream>>>(z, hits_g, deg, out);
}